// Round 6
// baseline (247.092 us; speedup 1.0000x reference)
//
#include <hip/hip_runtime.h>

// ---------------- problem constants ----------------
#define H_ 96
#define W_ 96
#define NTOK 9216            // H*W
#define CDIM 128
#define HS_ 48               // pooled H
#define NS_ 2304             // pooled tokens
#define LHEADS 4
#define HD_ 16
#define LD_ 64
#define SCALE_ 0.25f
#define KSPLIT 8
#define KEYS_PER_SPLIT 288   // NS_/KSPLIT
#define NPAIR 36864          // LHEADS*NTOK
#define NQB 144              // NTOK/64

// ---------------- avg pool 2x2 ----------------
__global__ __launch_bounds__(256)
void k_avgpool(const float* __restrict__ x, float* __restrict__ low) {
    int idx = blockIdx.x * 256 + threadIdx.x;     // over NS_*CDIM
    if (idx >= NS_ * CDIM) return;
    int c = idx & 127;
    int p = idx >> 7;
    int ws_ = p % HS_, hs = p / HS_;
    int base = ((2 * hs) * W_ + 2 * ws_) * CDIM + c;
    float s = x[base] + x[base + CDIM] + x[base + W_ * CDIM] + x[base + W_ * CDIM + CDIM];
    low[idx] = 0.25f * s;
}

// ---------------- high = restore(pixelshuffle(low)) + b - x ----------------
// one thread per output element; 4 elements/thread grid-stride within block.
// w staged transposed in LDS once per block (reads are stride-1 over o -> 2-way
// bank aliasing = free). low reads are wave-broadcast (same addr per 64 lanes).
__global__ __launch_bounds__(256)
void k_high(const float* __restrict__ x, const float* __restrict__ low,
            const float* __restrict__ rw, const float* __restrict__ rb,
            float* __restrict__ high) {
    __shared__ float w_s[32 * 128];   // w_s[ii*128+o] = rw[o*32+ii]
    int tid = threadIdx.x;
    #pragma unroll
    for (int k = 0; k < 16; ++k) {
        int idx = tid + k * 256;
        w_s[(idx & 31) * 128 + (idx >> 5)] = rw[idx];
    }
    __syncthreads();
    int base_i = blockIdx.x * 1024;           // 1024 elements per block
    #pragma unroll
    for (int k = 0; k < 4; ++k) {
        int idx = base_i + k * 256 + tid;     // over NTOK*CDIM
        int o = idx & 127;
        int n = idx >> 7;
        int h = n / W_, w = n % W_;
        int off = (h & 1) * 2 + (w & 1);
        const float* lrow = low + ((h >> 1) * HS_ + (w >> 1)) * CDIM + off;
        float acc = 0.f;
        #pragma unroll
        for (int ii = 0; ii < 32; ++ii) acc += lrow[ii * 4] * w_s[ii * 128 + o];
        high[idx] = acc + rb[o] - x[idx];
    }
}

// ---------------- generic tiled GEMM: C[m, n] = sum_k A[m,k]*Wt[n,k] + bias[n] ----------------
// BM=BN=64, BK=16, 256 threads, 4x4 per thread. M%64==0, N%64==0, K%16==0.
__global__ __launch_bounds__(256)
void k_gemm(const float* __restrict__ A, int lda,
            const float* __restrict__ Wt,          // (N,K) row-major
            const float* __restrict__ bias,        // may be null
            float* __restrict__ C, int ldc,
            int K) {
    __shared__ float As[16][68];
    __shared__ float Bs[16][68];
    int tid = threadIdx.x;
    int tx = tid & 15, ty = tid >> 4;
    int m0 = blockIdx.x * 64, n0 = blockIdx.y * 64;
    int lr = tid >> 2;           // 0..63  (row within tile)
    int lk = (tid & 3) * 4;      // 0,4,8,12 (k4 offset)
    float acc[4][4] = {};
    for (int kk = 0; kk < K; kk += 16) {
        float4 av = *(const float4*)&A[(m0 + lr) * lda + kk + lk];
        float4 bv = *(const float4*)&Wt[(n0 + lr) * K + kk + lk];
        As[lk + 0][lr] = av.x; As[lk + 1][lr] = av.y;
        As[lk + 2][lr] = av.z; As[lk + 3][lr] = av.w;
        Bs[lk + 0][lr] = bv.x; Bs[lk + 1][lr] = bv.y;
        Bs[lk + 2][lr] = bv.z; Bs[lk + 3][lr] = bv.w;
        __syncthreads();
        #pragma unroll
        for (int k = 0; k < 16; ++k) {
            float a[4], bb[4];
            *(float4*)a  = *(const float4*)&As[k][ty * 4];
            *(float4*)bb = *(const float4*)&Bs[k][tx * 4];
            #pragma unroll
            for (int i = 0; i < 4; ++i)
                #pragma unroll
                for (int j = 0; j < 4; ++j) acc[i][j] += a[i] * bb[j];
        }
        __syncthreads();
    }
    #pragma unroll
    for (int i = 0; i < 4; ++i) {
        int m = m0 + ty * 4 + i;
        #pragma unroll
        for (int j = 0; j < 4; ++j) {
            int n = n0 + tx * 4 + j;
            float v = acc[i][j];
            if (bias) v += bias[n];
            C[m * ldc + n] = v;
        }
    }
}

// ---------------- low-freq attention, key-split partial (max-free softmax) ----------------
// 256-thread blocks = 4 waves; each wave owns one split (4 consecutive splits
// per block) for the same (head, q-block). No barriers. K/V rows are
// WAVE-UNIFORM (wid via readfirstlane) -> scalar s_load path; inner loop is
// v_fmac with one SGPR operand. Workgroup-cap lesson (round 5): 64-thread
// blocks cap at ~16 waves/CU; 256-thread blocks allow up to 32.
// NOTE (round-4 lesson): do NOT software-pipeline — 128 live wave-uniform
// floats exceed the ~102-SGPR file (3x regression). Live set = one key-pair.
__global__ __launch_bounds__(256)
void k_lattn(const float* __restrict__ lq, const float* __restrict__ lkv,
             float* __restrict__ pacc, float* __restrict__ psum) {
    int bs = blockIdx.x;
    int g = bs & 1;                  // split group (0: splits 0-3, 1: splits 4-7)
    int rest = bs >> 1;
    int head = rest / NQB;
    int qb = rest % NQB;
    int wid = __builtin_amdgcn_readfirstlane(threadIdx.x >> 6);  // uniform wave id
    int split = g * 4 + wid;
    int q = qb * 64 + (threadIdx.x & 63);

    float qreg[HD_];
    #pragma unroll
    for (int d = 0; d < HD_; ++d) qreg[d] = lq[q * LD_ + head * HD_ + d] * SCALE_;

    float acc[HD_] = {};
    float lsum = 0.f;

    const int k0 = split * KEYS_PER_SPLIT;
    for (int kk = 0; kk < KEYS_PER_SPLIT; kk += 2) {
        const float* kp = lkv + (size_t)(k0 + kk) * CDIM + head * HD_;  // wave-uniform
        float ka[HD_], kb[HD_];
        #pragma unroll
        for (int d = 0; d < HD_; ++d) { ka[d] = kp[d]; kb[d] = kp[CDIM + d]; }
        float sa0 = 0.f, sa1 = 0.f, sa2 = 0.f, sa3 = 0.f;
        float sb0 = 0.f, sb1 = 0.f, sb2 = 0.f, sb3 = 0.f;
        #pragma unroll
        for (int d = 0; d < HD_; d += 4) {
            sa0 += qreg[d + 0] * ka[d + 0];
            sa1 += qreg[d + 1] * ka[d + 1];
            sa2 += qreg[d + 2] * ka[d + 2];
            sa3 += qreg[d + 3] * ka[d + 3];
            sb0 += qreg[d + 0] * kb[d + 0];
            sb1 += qreg[d + 1] * kb[d + 1];
            sb2 += qreg[d + 2] * kb[d + 2];
            sb3 += qreg[d + 3] * kb[d + 3];
        }
        float va[HD_], vb[HD_];
        #pragma unroll
        for (int d = 0; d < HD_; ++d) { va[d] = kp[LD_ + d]; vb[d] = kp[CDIM + LD_ + d]; }
        float ea = __expf((sa0 + sa1) + (sa2 + sa3));
        float eb = __expf((sb0 + sb1) + (sb2 + sb3));
        lsum += ea + eb;
        #pragma unroll
        for (int d = 0; d < HD_; ++d) acc[d] += ea * va[d];
        #pragma unroll
        for (int d = 0; d < HD_; ++d) acc[d] += eb * vb[d];
    }
    int p = head * NTOK + q;
    #pragma unroll
    for (int d = 0; d < HD_; ++d) pacc[(size_t)(split * NPAIR + p) * HD_ + d] = acc[d];
    psum[(size_t)split * NPAIR + p] = lsum;
}

__global__ __launch_bounds__(256)
void k_lattn_combine(const float* __restrict__ pacc, const float* __restrict__ psum,
                     float* __restrict__ lout) {
    int idx = blockIdx.x * 256 + threadIdx.x;   // over NPAIR*HD_
    if (idx >= NPAIR * HD_) return;
    int p = idx >> 4, d = idx & 15;
    float a = 0.f, s = 0.f;
    #pragma unroll
    for (int sp = 0; sp < KSPLIT; ++sp) a += pacc[(size_t)(sp * NPAIR + p) * HD_ + d];
    #pragma unroll
    for (int sp = 0; sp < KSPLIT; ++sp) s += psum[(size_t)sp * NPAIR + p];
    int head = p / NTOK, q = p % NTOK;
    lout[q * LD_ + head * HD_ + d] = a / s;
}

// ---------------- high-freq 2x2 windowed attention ----------------
// one thread per (window, head, query-token): 2304*4*4 = 36864
__global__ __launch_bounds__(256)
void k_hattn(const float* __restrict__ qkv, float* __restrict__ ho) {
    int idx = blockIdx.x * 256 + threadIdx.x;
    if (idx >= NPAIR) return;
    int t = idx & 3;
    int hh = (idx >> 2) & 3;
    int g = idx >> 4;
    int gh = g / 48, gw = g % 48;
    int nq = (2 * gh + (t >> 1)) * W_ + 2 * gw + (t & 1);
    float q[HD_];
    #pragma unroll
    for (int d = 0; d < HD_; ++d) q[d] = qkv[nq * 192 + hh * HD_ + d];
    float e[4], esum = 0.f;
    int nk[4];
    #pragma unroll
    for (int kt = 0; kt < 4; ++kt) {
        nk[kt] = (2 * gh + (kt >> 1)) * W_ + 2 * gw + (kt & 1);
        float s = 0.f;
        #pragma unroll
        for (int d = 0; d < HD_; ++d) s += q[d] * qkv[nk[kt] * 192 + 64 + hh * HD_ + d];
        e[kt] = __expf(s * SCALE_);
        esum += e[kt];
    }
    float inv = 1.f / esum;
    float o[HD_] = {};
    #pragma unroll
    for (int kt = 0; kt < 4; ++kt) {
        float pkt = e[kt] * inv;
        #pragma unroll
        for (int d = 0; d < HD_; ++d) o[d] += pkt * qkv[nk[kt] * 192 + 128 + hh * HD_ + d];
    }
    #pragma unroll
    for (int d = 0; d < HD_; ++d) ho[nq * 64 + hh * HD_ + d] = o[d];
}

// ---------------- launch ----------------
// Workspace aliasing (floats). pacc (KSPLIT*589824 = 4,718,592) overlaps the
// high-path buffers, which are all dead before k_lattn runs:
//   pacc  = [0 .. 4718592)            overlaps low/high/hqkv/ho
//   psum  = [4718592 .. 5013504)
//   lkv   = [5013504 .. 5308416)      live into lattn
//   lq    = [5308416 .. 5898240)      live into lattn
//   lout  = [5898240 .. 6488064)
// total 6,488,064 floats = 25.95 MB (validated)
extern "C" void kernel_launch(void* const* d_in, const int* in_sizes, int n_in,
                              void* d_out, int out_size, void* d_ws, size_t ws_size,
                              hipStream_t stream) {
    const float* x        = (const float*)d_in[0];
    const float* restore_w = (const float*)d_in[1];
    const float* restore_b = (const float*)d_in[2];
    const float* l_q_w    = (const float*)d_in[3];
    const float* l_kv_w   = (const float*)d_in[4];
    const float* l_proj_w = (const float*)d_in[5];
    const float* l_proj_b = (const float*)d_in[6];
    const float* h_qkv_w  = (const float*)d_in[7];
    const float* h_proj_w = (const float*)d_in[8];
    const float* h_proj_b = (const float*)d_in[9];
    float* out = (float*)d_out;

    float* ws    = (float*)d_ws;
    float* low   = ws;
    float* high  = ws + 294912;
    float* hqkv  = ws + 1474560;
    float* ho    = ws + 3244032;
    float* pacc  = ws;                   // aliases low/high/hqkv/ho (dead by then)
    float* psum  = ws + 4718592;
    float* lkv   = ws + 5013504;
    float* lq    = ws + 5308416;
    float* lout  = ws + 5898240;

    // ---- shared prep ----
    k_avgpool<<<(NS_ * CDIM + 255) / 256, 256, 0, stream>>>(x, low);
    k_high<<<NTOK * CDIM / 1024, 256, 0, stream>>>(x, low, restore_w, restore_b, high);
    // lkv = low @ l_kv_w.T  (2304 x 128, K=128)   [low dead after]
    k_gemm<<<dim3(NS_ / 64, 2), 256, 0, stream>>>(low, CDIM, l_kv_w, nullptr, lkv, CDIM, CDIM);

    // ---- high path first (frees its buffers for pacc) ----
    // hqkv = high @ h_qkv_w.T  (9216 x 192, K=128)   [high dead after]
    k_gemm<<<dim3(NTOK / 64, 3), 256, 0, stream>>>(high, CDIM, h_qkv_w, nullptr, hqkv, 192, CDIM);
    k_hattn<<<(NPAIR + 255) / 256, 256, 0, stream>>>(hqkv, ho);          // [hqkv dead]
    // hx = ho @ h_proj_w.T + b -> out[:, 64:128]      [ho dead after]
    k_gemm<<<dim3(NTOK / 64, 1), 256, 0, stream>>>(ho, LD_, h_proj_w, h_proj_b, out + 64, CDIM, LD_);

    // ---- low path ----
    // lq = x @ l_q_w.T  (9216 x 64, K=128)
    k_gemm<<<dim3(NTOK / 64, 1), 256, 0, stream>>>(x, CDIM, l_q_w, nullptr, lq, LD_, CDIM);
    // 1152 blocks x 4 waves (4 splits each)
    k_lattn<<<LHEADS * NQB * (KSPLIT / 4), 256, 0, stream>>>(lq, lkv, pacc, psum);
    k_lattn_combine<<<(NPAIR * HD_ + 255) / 256, 256, 0, stream>>>(pacc, psum, lout);
    // lx = lout @ l_proj_w.T + b -> out[:, 0:64]
    k_gemm<<<dim3(NTOK / 64, 1), 256, 0, stream>>>(lout, LD_, l_proj_w, l_proj_b, out, CDIM, LD_);
}

// Round 7
// 238.618 us; speedup vs baseline: 1.0355x; 1.0355x over previous
//
#include <hip/hip_runtime.h>

// ---------------- problem constants ----------------
#define H_ 96
#define W_ 96
#define NTOK 9216            // H*W
#define CDIM 128
#define HS_ 48               // pooled H
#define NS_ 2304             // pooled tokens
#define LHEADS 4
#define HD_ 16
#define LD_ 64
#define SCALE_ 0.25f
#define KSPLIT 8
#define KEYS_PER_SPLIT 288   // NS_/KSPLIT
#define NPAIR 36864          // LHEADS*NTOK
#define NQB256 36            // NTOK/256

// ---------------- avg pool 2x2 ----------------
__global__ __launch_bounds__(256)
void k_avgpool(const float* __restrict__ x, float* __restrict__ low) {
    int idx = blockIdx.x * 256 + threadIdx.x;     // over NS_*CDIM
    if (idx >= NS_ * CDIM) return;
    int c = idx & 127;
    int p = idx >> 7;
    int ws_ = p % HS_, hs = p / HS_;
    int base = ((2 * hs) * W_ + 2 * ws_) * CDIM + c;
    float s = x[base] + x[base + CDIM] + x[base + W_ * CDIM] + x[base + W_ * CDIM + CDIM];
    low[idx] = 0.25f * s;
}

// ---------------- high = restore(pixelshuffle(low)) + b - x ----------------
// one thread per output element; 4 elements/thread grid-stride within block.
__global__ __launch_bounds__(256)
void k_high(const float* __restrict__ x, const float* __restrict__ low,
            const float* __restrict__ rw, const float* __restrict__ rb,
            float* __restrict__ high) {
    __shared__ float w_s[32 * 128];   // w_s[ii*128+o] = rw[o*32+ii]
    int tid = threadIdx.x;
    #pragma unroll
    for (int k = 0; k < 16; ++k) {
        int idx = tid + k * 256;
        w_s[(idx & 31) * 128 + (idx >> 5)] = rw[idx];
    }
    __syncthreads();
    int base_i = blockIdx.x * 1024;           // 1024 elements per block
    #pragma unroll
    for (int k = 0; k < 4; ++k) {
        int idx = base_i + k * 256 + tid;     // over NTOK*CDIM
        int o = idx & 127;
        int n = idx >> 7;
        int h = n / W_, w = n % W_;
        int off = (h & 1) * 2 + (w & 1);
        const float* lrow = low + ((h >> 1) * HS_ + (w >> 1)) * CDIM + off;
        float acc = 0.f;
        #pragma unroll
        for (int ii = 0; ii < 32; ++ii) acc += lrow[ii * 4] * w_s[ii * 128 + o];
        high[idx] = acc + rb[o] - x[idx];
    }
}

// ---------------- generic tiled GEMM: C[m, n] = sum_k A[m,k]*Wt[n,k] + bias[n] ----------------
// BM=BN=64, BK=16, 256 threads, 4x4 per thread. M%64==0, N%64==0, K%16==0.
__global__ __launch_bounds__(256)
void k_gemm(const float* __restrict__ A, int lda,
            const float* __restrict__ Wt,          // (N,K) row-major
            const float* __restrict__ bias,        // may be null
            float* __restrict__ C, int ldc,
            int K) {
    __shared__ float As[16][68];
    __shared__ float Bs[16][68];
    int tid = threadIdx.x;
    int tx = tid & 15, ty = tid >> 4;
    int m0 = blockIdx.x * 64, n0 = blockIdx.y * 64;
    int lr = tid >> 2;           // 0..63  (row within tile)
    int lk = (tid & 3) * 4;      // 0,4,8,12 (k4 offset)
    float acc[4][4] = {};
    for (int kk = 0; kk < K; kk += 16) {
        float4 av = *(const float4*)&A[(m0 + lr) * lda + kk + lk];
        float4 bv = *(const float4*)&Wt[(n0 + lr) * K + kk + lk];
        As[lk + 0][lr] = av.x; As[lk + 1][lr] = av.y;
        As[lk + 2][lr] = av.z; As[lk + 3][lr] = av.w;
        Bs[lk + 0][lr] = bv.x; Bs[lk + 1][lr] = bv.y;
        Bs[lk + 2][lr] = bv.z; Bs[lk + 3][lr] = bv.w;
        __syncthreads();
        #pragma unroll
        for (int k = 0; k < 16; ++k) {
            float a[4], bb[4];
            *(float4*)a  = *(const float4*)&As[k][ty * 4];
            *(float4*)bb = *(const float4*)&Bs[k][tx * 4];
            #pragma unroll
            for (int i = 0; i < 4; ++i)
                #pragma unroll
                for (int j = 0; j < 4; ++j) acc[i][j] += a[i] * bb[j];
        }
        __syncthreads();
    }
    #pragma unroll
    for (int i = 0; i < 4; ++i) {
        int m = m0 + ty * 4 + i;
        #pragma unroll
        for (int j = 0; j < 4; ++j) {
            int n = n0 + tx * 4 + j;
            float v = acc[i][j];
            if (bias) v += bias[n];
            C[m * ldc + n] = v;
        }
    }
}

// ---------------- low-freq attention, key-split partial (max-free softmax) ----------------
// 256-thread blocks = 4 waves, ALL on the SAME (head, split) covering 256
// consecutive queries. All 4 waves issue s_loads for IDENTICAL addresses:
// first wave misses to L2, the rest hit scalar-L1 / MSHR-coalesce, and
// progress skew between waves pipelines the stream. (Round-6 lesson: 4
// disjoint streams per CU thrash sL1 and correlate stalls — regression.)
// NOTE (round-4 lesson): do NOT software-pipeline — live set must stay at
// one key-pair (64 wave-uniform floats) or the compiler demotes to scratch.
__global__ __launch_bounds__(256)
void k_lattn(const float* __restrict__ lq, const float* __restrict__ lkv,
             float* __restrict__ pacc, float* __restrict__ psum) {
    int bs = blockIdx.x;
    int split = bs % KSPLIT;
    int rest = bs / KSPLIT;
    int head = rest / NQB256;
    int qb = rest % NQB256;
    int q = qb * 256 + threadIdx.x;

    float qreg[HD_];
    #pragma unroll
    for (int d = 0; d < HD_; ++d) qreg[d] = lq[q * LD_ + head * HD_ + d] * SCALE_;

    float acc[HD_] = {};
    float lsum = 0.f;

    const int k0 = split * KEYS_PER_SPLIT;
    for (int kk = 0; kk < KEYS_PER_SPLIT; kk += 2) {
        const float* kp = lkv + (size_t)(k0 + kk) * CDIM + head * HD_;  // block-uniform
        float ka[HD_], kb[HD_];
        #pragma unroll
        for (int d = 0; d < HD_; ++d) { ka[d] = kp[d]; kb[d] = kp[CDIM + d]; }
        float sa0 = 0.f, sa1 = 0.f, sa2 = 0.f, sa3 = 0.f;
        float sb0 = 0.f, sb1 = 0.f, sb2 = 0.f, sb3 = 0.f;
        #pragma unroll
        for (int d = 0; d < HD_; d += 4) {
            sa0 += qreg[d + 0] * ka[d + 0];
            sa1 += qreg[d + 1] * ka[d + 1];
            sa2 += qreg[d + 2] * ka[d + 2];
            sa3 += qreg[d + 3] * ka[d + 3];
            sb0 += qreg[d + 0] * kb[d + 0];
            sb1 += qreg[d + 1] * kb[d + 1];
            sb2 += qreg[d + 2] * kb[d + 2];
            sb3 += qreg[d + 3] * kb[d + 3];
        }
        float va[HD_], vb[HD_];
        #pragma unroll
        for (int d = 0; d < HD_; ++d) { va[d] = kp[LD_ + d]; vb[d] = kp[CDIM + LD_ + d]; }
        float ea = __expf((sa0 + sa1) + (sa2 + sa3));
        float eb = __expf((sb0 + sb1) + (sb2 + sb3));
        lsum += ea + eb;
        #pragma unroll
        for (int d = 0; d < HD_; ++d) acc[d] += ea * va[d];
        #pragma unroll
        for (int d = 0; d < HD_; ++d) acc[d] += eb * vb[d];
    }
    int p = head * NTOK + q;
    #pragma unroll
    for (int d = 0; d < HD_; ++d) pacc[(size_t)(split * NPAIR + p) * HD_ + d] = acc[d];
    psum[(size_t)split * NPAIR + p] = lsum;
}

__global__ __launch_bounds__(256)
void k_lattn_combine(const float* __restrict__ pacc, const float* __restrict__ psum,
                     float* __restrict__ lout) {
    int idx = blockIdx.x * 256 + threadIdx.x;   // over NPAIR*HD_
    if (idx >= NPAIR * HD_) return;
    int p = idx >> 4, d = idx & 15;
    float a = 0.f, s = 0.f;
    #pragma unroll
    for (int sp = 0; sp < KSPLIT; ++sp) a += pacc[(size_t)(sp * NPAIR + p) * HD_ + d];
    #pragma unroll
    for (int sp = 0; sp < KSPLIT; ++sp) s += psum[(size_t)sp * NPAIR + p];
    int head = p / NTOK, q = p % NTOK;
    lout[q * LD_ + head * HD_ + d] = a / s;
}

// ---------------- high-freq 2x2 windowed attention ----------------
// one thread per (window, head, query-token): 2304*4*4 = 36864
__global__ __launch_bounds__(256)
void k_hattn(const float* __restrict__ qkv, float* __restrict__ ho) {
    int idx = blockIdx.x * 256 + threadIdx.x;
    if (idx >= NPAIR) return;
    int t = idx & 3;
    int hh = (idx >> 2) & 3;
    int g = idx >> 4;
    int gh = g / 48, gw = g % 48;
    int nq = (2 * gh + (t >> 1)) * W_ + 2 * gw + (t & 1);
    float q[HD_];
    #pragma unroll
    for (int d = 0; d < HD_; ++d) q[d] = qkv[nq * 192 + hh * HD_ + d];
    float e[4], esum = 0.f;
    int nk[4];
    #pragma unroll
    for (int kt = 0; kt < 4; ++kt) {
        nk[kt] = (2 * gh + (kt >> 1)) * W_ + 2 * gw + (kt & 1);
        float s = 0.f;
        #pragma unroll
        for (int d = 0; d < HD_; ++d) s += q[d] * qkv[nk[kt] * 192 + 64 + hh * HD_ + d];
        e[kt] = __expf(s * SCALE_);
        esum += e[kt];
    }
    float inv = 1.f / esum;
    float o[HD_] = {};
    #pragma unroll
    for (int kt = 0; kt < 4; ++kt) {
        float pkt = e[kt] * inv;
        #pragma unroll
        for (int d = 0; d < HD_; ++d) o[d] += pkt * qkv[nk[kt] * 192 + 128 + hh * HD_ + d];
    }
    #pragma unroll
    for (int d = 0; d < HD_; ++d) ho[nq * 64 + hh * HD_ + d] = o[d];
}

// ---------------- launch ----------------
// Workspace aliasing (floats). pacc (KSPLIT*589824 = 4,718,592) overlaps the
// high-path buffers, which are all dead before k_lattn runs:
//   pacc  = [0 .. 4718592)            overlaps low/high/hqkv/ho
//   psum  = [4718592 .. 5013504)
//   lkv   = [5013504 .. 5308416)      live into lattn
//   lq    = [5308416 .. 5898240)      live into lattn
//   lout  = [5898240 .. 6488064)
// total 6,488,064 floats = 25.95 MB (validated)
extern "C" void kernel_launch(void* const* d_in, const int* in_sizes, int n_in,
                              void* d_out, int out_size, void* d_ws, size_t ws_size,
                              hipStream_t stream) {
    const float* x        = (const float*)d_in[0];
    const float* restore_w = (const float*)d_in[1];
    const float* restore_b = (const float*)d_in[2];
    const float* l_q_w    = (const float*)d_in[3];
    const float* l_kv_w   = (const float*)d_in[4];
    const float* l_proj_w = (const float*)d_in[5];
    const float* l_proj_b = (const float*)d_in[6];
    const float* h_qkv_w  = (const float*)d_in[7];
    const float* h_proj_w = (const float*)d_in[8];
    const float* h_proj_b = (const float*)d_in[9];
    float* out = (float*)d_out;

    float* ws    = (float*)d_ws;
    float* low   = ws;
    float* high  = ws + 294912;
    float* hqkv  = ws + 1474560;
    float* ho    = ws + 3244032;
    float* pacc  = ws;                   // aliases low/high/hqkv/ho (dead by then)
    float* psum  = ws + 4718592;
    float* lkv   = ws + 5013504;
    float* lq    = ws + 5308416;
    float* lout  = ws + 5898240;

    // ---- shared prep ----
    k_avgpool<<<(NS_ * CDIM + 255) / 256, 256, 0, stream>>>(x, low);
    k_high<<<NTOK * CDIM / 1024, 256, 0, stream>>>(x, low, restore_w, restore_b, high);
    // lkv = low @ l_kv_w.T  (2304 x 128, K=128)   [low dead after]
    k_gemm<<<dim3(NS_ / 64, 2), 256, 0, stream>>>(low, CDIM, l_kv_w, nullptr, lkv, CDIM, CDIM);

    // ---- high path first (frees its buffers for pacc) ----
    // hqkv = high @ h_qkv_w.T  (9216 x 192, K=128)   [high dead after]
    k_gemm<<<dim3(NTOK / 64, 3), 256, 0, stream>>>(high, CDIM, h_qkv_w, nullptr, hqkv, 192, CDIM);
    k_hattn<<<(NPAIR + 255) / 256, 256, 0, stream>>>(hqkv, ho);          // [hqkv dead]
    // hx = ho @ h_proj_w.T + b -> out[:, 64:128]      [ho dead after]
    k_gemm<<<dim3(NTOK / 64, 1), 256, 0, stream>>>(ho, LD_, h_proj_w, h_proj_b, out + 64, CDIM, LD_);

    // ---- low path ----
    // lq = x @ l_q_w.T  (9216 x 64, K=128)
    k_gemm<<<dim3(NTOK / 64, 1), 256, 0, stream>>>(x, CDIM, l_q_w, nullptr, lq, LD_, CDIM);
    // 1152 blocks x 256T; 4 waves per block share one (head, split) stream
    k_lattn<<<LHEADS * NQB256 * KSPLIT, 256, 0, stream>>>(lq, lkv, pacc, psum);
    k_lattn_combine<<<(NPAIR * HD_ + 255) / 256, 256, 0, stream>>>(pacc, psum, lout);
    // lx = lout @ l_proj_w.T + b -> out[:, 0:64]
    k_gemm<<<dim3(NTOK / 64, 1), 256, 0, stream>>>(lout, LD_, l_proj_w, l_proj_b, out, CDIM, LD_);
}

// Round 11
// 182.070 us; speedup vs baseline: 1.3571x; 1.3106x over previous
//
#include <hip/hip_runtime.h>

// ---------------- problem constants ----------------
#define H_ 96
#define W_ 96
#define NTOK 9216            // H*W
#define CDIM 128
#define HS_ 48               // pooled H
#define NS_ 2304             // pooled tokens
#define LHEADS 4
#define HD_ 16
#define LD_ 64
#define SCALE_ 0.25f
#define NPAIR 36864          // LHEADS*NTOK

typedef __attribute__((ext_vector_type(8))) short short8b;  // 8 x bf16
typedef __attribute__((ext_vector_type(4))) float f32x4;
typedef unsigned short ushort_t;

__device__ inline ushort_t f2bf(float x) {   // RNE float->bf16
    union { float f; unsigned u; } v; v.f = x;
    unsigned r = v.u + 0x7FFF + ((v.u >> 16) & 1);
    return (ushort_t)(r >> 16);
}

// ---------------- avg pool 2x2 ----------------
__global__ __launch_bounds__(256)
void k_avgpool(const float* __restrict__ x, float* __restrict__ low) {
    int idx = blockIdx.x * 256 + threadIdx.x;     // over NS_*CDIM
    if (idx >= NS_ * CDIM) return;
    int c = idx & 127;
    int p = idx >> 7;
    int ws_ = p % HS_, hs = p / HS_;
    int base = ((2 * hs) * W_ + 2 * ws_) * CDIM + c;
    float s = x[base] + x[base + CDIM] + x[base + W_ * CDIM] + x[base + W_ * CDIM + CDIM];
    low[idx] = 0.25f * s;
}

// ---------------- high = restore(pixelshuffle(low)) + b - x ----------------
__global__ __launch_bounds__(256)
void k_high(const float* __restrict__ x, const float* __restrict__ low,
            const float* __restrict__ rw, const float* __restrict__ rb,
            float* __restrict__ high) {
    __shared__ float w_s[32 * 128];   // w_s[ii*128+o] = rw[o*32+ii]
    int tid = threadIdx.x;
    #pragma unroll
    for (int k = 0; k < 16; ++k) {
        int idx = tid + k * 256;
        w_s[(idx & 31) * 128 + (idx >> 5)] = rw[idx];
    }
    __syncthreads();
    int base_i = blockIdx.x * 1024;           // 1024 elements per block
    #pragma unroll
    for (int k = 0; k < 4; ++k) {
        int idx = base_i + k * 256 + tid;     // over NTOK*CDIM
        int o = idx & 127;
        int n = idx >> 7;
        int h = n / W_, w = n % W_;
        int off = (h & 1) * 2 + (w & 1);
        const float* lrow = low + ((h >> 1) * HS_ + (w >> 1)) * CDIM + off;
        float acc = 0.f;
        #pragma unroll
        for (int ii = 0; ii < 32; ++ii) acc += lrow[ii * 4] * w_s[ii * 128 + o];
        high[idx] = acc + rb[o] - x[idx];
    }
}

// ---------------- generic tiled GEMM (fp32 out) ----------------
// BM=BN=64, BK=16, 256 threads, 4x4 per thread.
__global__ __launch_bounds__(256)
void k_gemm(const float* __restrict__ A, int lda,
            const float* __restrict__ Wt,          // (N,K) row-major
            const float* __restrict__ bias,        // may be null
            float* __restrict__ C, int ldc,
            int K) {
    __shared__ float As[16][68];
    __shared__ float Bs[16][68];
    int tid = threadIdx.x;
    int tx = tid & 15, ty = tid >> 4;
    int m0 = blockIdx.x * 64, n0 = blockIdx.y * 64;
    int lr = tid >> 2;
    int lk = (tid & 3) * 4;
    float acc[4][4] = {};
    for (int kk = 0; kk < K; kk += 16) {
        float4 av = *(const float4*)&A[(m0 + lr) * lda + kk + lk];
        float4 bv = *(const float4*)&Wt[(n0 + lr) * K + kk + lk];
        As[lk + 0][lr] = av.x; As[lk + 1][lr] = av.y;
        As[lk + 2][lr] = av.z; As[lk + 3][lr] = av.w;
        Bs[lk + 0][lr] = bv.x; Bs[lk + 1][lr] = bv.y;
        Bs[lk + 2][lr] = bv.z; Bs[lk + 3][lr] = bv.w;
        __syncthreads();
        #pragma unroll
        for (int k = 0; k < 16; ++k) {
            float a[4], bb[4];
            *(float4*)a  = *(const float4*)&As[k][ty * 4];
            *(float4*)bb = *(const float4*)&Bs[k][tx * 4];
            #pragma unroll
            for (int i = 0; i < 4; ++i)
                #pragma unroll
                for (int j = 0; j < 4; ++j) acc[i][j] += a[i] * bb[j];
        }
        __syncthreads();
    }
    #pragma unroll
    for (int i = 0; i < 4; ++i) {
        int m = m0 + ty * 4 + i;
        #pragma unroll
        for (int j = 0; j < 4; ++j) {
            int n = n0 + tx * 4 + j;
            float v = acc[i][j];
            if (bias) v += bias[n];
            C[m * ldc + n] = v;
        }
    }
}

// ---------------- lq GEMM -> Qb bf16 [4][NTOK][16], SCALE folded ----------------
__global__ __launch_bounds__(256)
void k_gemm_q(const float* __restrict__ A,           // x (NTOK x 128)
              const float* __restrict__ Wt,          // l_q_w (64 x 128)
              ushort_t* __restrict__ Qb) {
    __shared__ float As[16][68];
    __shared__ float Bs[16][68];
    int tid = threadIdx.x;
    int tx = tid & 15, ty = tid >> 4;
    int m0 = blockIdx.x * 64;
    int lr = tid >> 2;
    int lk = (tid & 3) * 4;
    float acc[4][4] = {};
    for (int kk = 0; kk < CDIM; kk += 16) {
        float4 av = *(const float4*)&A[(m0 + lr) * CDIM + kk + lk];
        float4 bv = *(const float4*)&Wt[lr * CDIM + kk + lk];
        As[lk + 0][lr] = av.x; As[lk + 1][lr] = av.y;
        As[lk + 2][lr] = av.z; As[lk + 3][lr] = av.w;
        Bs[lk + 0][lr] = bv.x; Bs[lk + 1][lr] = bv.y;
        Bs[lk + 2][lr] = bv.z; Bs[lk + 3][lr] = bv.w;
        __syncthreads();
        #pragma unroll
        for (int k = 0; k < 16; ++k) {
            float a[4], bb[4];
            *(float4*)a  = *(const float4*)&As[k][ty * 4];
            *(float4*)bb = *(const float4*)&Bs[k][tx * 4];
            #pragma unroll
            for (int i = 0; i < 4; ++i)
                #pragma unroll
                for (int j = 0; j < 4; ++j) acc[i][j] += a[i] * bb[j];
        }
        __syncthreads();
    }
    #pragma unroll
    for (int i = 0; i < 4; ++i) {
        int m = m0 + ty * 4 + i;
        #pragma unroll
        for (int j = 0; j < 4; ++j) {
            int n = tx * 4 + j;              // 0..63
            int h = n >> 4, d = n & 15;
            Qb[((size_t)h * NTOK + m) * 16 + d] = f2bf(acc[i][j] * SCALE_);
        }
    }
}

// ---------------- lkv GEMM -> Kb bf16 [4][NS][16], Vt bf16 [4][16][NS] ----------------
__global__ __launch_bounds__(256)
void k_gemm_kv(const float* __restrict__ A,           // low (NS x 128)
               const float* __restrict__ Wt,          // l_kv_w (128 x 128)
               ushort_t* __restrict__ Kb, ushort_t* __restrict__ Vt) {
    __shared__ float As[16][68];
    __shared__ float Bs[16][68];
    int tid = threadIdx.x;
    int tx = tid & 15, ty = tid >> 4;
    int m0 = blockIdx.x * 64, n0 = blockIdx.y * 64;
    int lr = tid >> 2;
    int lk = (tid & 3) * 4;
    float acc[4][4] = {};
    for (int kk = 0; kk < CDIM; kk += 16) {
        float4 av = *(const float4*)&A[(m0 + lr) * CDIM + kk + lk];
        float4 bv = *(const float4*)&Wt[(n0 + lr) * CDIM + kk + lk];
        As[lk + 0][lr] = av.x; As[lk + 1][lr] = av.y;
        As[lk + 2][lr] = av.z; As[lk + 3][lr] = av.w;
        Bs[lk + 0][lr] = bv.x; Bs[lk + 1][lr] = bv.y;
        Bs[lk + 2][lr] = bv.z; Bs[lk + 3][lr] = bv.w;
        __syncthreads();
        #pragma unroll
        for (int k = 0; k < 16; ++k) {
            float a[4], bb[4];
            *(float4*)a  = *(const float4*)&As[k][ty * 4];
            *(float4*)bb = *(const float4*)&Bs[k][tx * 4];
            #pragma unroll
            for (int i = 0; i < 4; ++i)
                #pragma unroll
                for (int j = 0; j < 4; ++j) acc[i][j] += a[i] * bb[j];
        }
        __syncthreads();
    }
    #pragma unroll
    for (int i = 0; i < 4; ++i) {
        int m = m0 + ty * 4 + i;
        #pragma unroll
        for (int j = 0; j < 4; ++j) {
            int n = n0 + tx * 4 + j;          // 0..127
            ushort_t v = f2bf(acc[i][j]);
            if (n < 64) {                     // K part
                int h = n >> 4, d = n & 15;
                Kb[((size_t)h * NS_ + m) * 16 + d] = v;
            } else {                          // V part, transposed
                int h = (n - 64) >> 4, d = (n - 64) & 15;
                Vt[((size_t)h * 16 + d) * NS_ + m] = v;
            }
        }
    }
}

// ---------------- low-freq attention: bf16 MFMA flash (max-free softmax) ----------------
// 256T = 4 independent waves; wave = 16 queries x all 2304 keys, one head.
// Per 32-key tile: 2x mfma_f32_16x16x32_bf16 QK^T (d=16, upper contraction
// half zero-padded), exp in fp32, P->bf16 via private 1KB LDS slice (no
// barriers; DS ops are in-order within a wave), 1 full-K PV MFMA into a
// 4-reg fp32 accumulator. K/V frags are double-buffered VGPR vector loads
// (round-4 lesson: never pipeline via SGPRs). Fragment layouts
// (guide-verified): A/B lane=(g,c): row/col=c, k=8g+e ; C: col=c, row=4g+r.
__global__ __launch_bounds__(256)
void k_lattn_mfma(const ushort_t* __restrict__ Qb, const ushort_t* __restrict__ Kb,
                  const ushort_t* __restrict__ Vt, float* __restrict__ lout) {
    __shared__ __align__(16) ushort_t P_lds[4][16][32];
    int tid = threadIdx.x;
    int wid = tid >> 6;
    int lane = tid & 63;
    int g = lane >> 4, c = lane & 15;
    int head = blockIdx.x / (NTOK / 64);
    int qb = blockIdx.x % (NTOK / 64);
    int q0 = qb * 64 + wid * 16;

    short8b zf = {0, 0, 0, 0, 0, 0, 0, 0};
    f32x4 zc = {0.f, 0.f, 0.f, 0.f};

    // Q A-frag (persistent): row=c, k=8g+e; zero for k>=16
    short8b qfrag = zf;
    if (g < 2)
        qfrag = *(const short8b*)(Qb + ((size_t)head * NTOK + q0 + c) * 16 + g * 8);

    const ushort_t* kbase = Kb + (size_t)head * NS_ * 16;
    const ushort_t* vbase = Vt + ((size_t)head * 16 + c) * NS_;

    f32x4 o = zc;
    float lsum[4] = {0.f, 0.f, 0.f, 0.f};

#define LOADT(KA, KB, VV, kt) do {                                            \
    if (g < 2) {                                                              \
        KA = *(const short8b*)(kbase + ((kt) + c) * 16 + g * 8);              \
        KB = *(const short8b*)(kbase + ((kt) + 16 + c) * 16 + g * 8);         \
    } else { KA = zf; KB = zf; }                                              \
    VV = *(const short8b*)(vbase + (kt) + 8 * g);                             \
} while (0)

#define COMPT(KA, KB, VV) do {                                                \
    f32x4 s0 = __builtin_amdgcn_mfma_f32_16x16x32_bf16(qfrag, KA, zc, 0, 0, 0); \
    f32x4 s1 = __builtin_amdgcn_mfma_f32_16x16x32_bf16(qfrag, KB, zc, 0, 0, 0); \
    _Pragma("unroll")                                                         \
    for (int r = 0; r < 4; ++r) {                                             \
        float p0 = __expf(s0[r]);                                             \
        float p1 = __expf(s1[r]);                                             \
        lsum[r] += p0 + p1;                                                   \
        P_lds[wid][4 * g + r][c] = f2bf(p0);                                  \
        P_lds[wid][4 * g + r][16 + c] = f2bf(p1);                             \
    }                                                                         \
    short8b pa = *(const short8b*)&P_lds[wid][c][8 * g];                      \
    o = __builtin_amdgcn_mfma_f32_16x16x32_bf16(pa, VV, o, 0, 0, 0);          \
} while (0)

    short8b kA, kB, vA, kA2, kB2, vA2;
    LOADT(kA, kB, vA, 0);
    int kt = 0;
    for (kt = 0; kt + 64 < NS_; kt += 64) {
        LOADT(kA2, kB2, vA2, kt + 32);
        COMPT(kA, kB, vA);
        LOADT(kA, kB, vA, kt + 64);
        COMPT(kA2, kB2, vA2);
    }
    LOADT(kA2, kB2, vA2, kt + 32);
    COMPT(kA, kB, vA);
    COMPT(kA2, kB2, vA2);
#undef LOADT
#undef COMPT

    // row-sum over the 16 cols (lanes c=0..15 within group g), then write
    #pragma unroll
    for (int r = 0; r < 4; ++r) {
        float s = lsum[r];
        s += __shfl_xor(s, 1);
        s += __shfl_xor(s, 2);
        s += __shfl_xor(s, 4);
        s += __shfl_xor(s, 8);
        lout[(size_t)(q0 + 4 * g + r) * LD_ + head * HD_ + c] = o[r] / s;
    }
}

// ---------------- high-freq 2x2 windowed attention ----------------
__global__ __launch_bounds__(256)
void k_hattn(const float* __restrict__ qkv, float* __restrict__ ho) {
    int idx = blockIdx.x * 256 + threadIdx.x;
    if (idx >= NPAIR) return;
    int t = idx & 3;
    int hh = (idx >> 2) & 3;
    int g = idx >> 4;
    int gh = g / 48, gw = g % 48;
    int nq = (2 * gh + (t >> 1)) * W_ + 2 * gw + (t & 1);
    float q[HD_];
    #pragma unroll
    for (int d = 0; d < HD_; ++d) q[d] = qkv[nq * 192 + hh * HD_ + d];
    float e[4], esum = 0.f;
    int nk[4];
    #pragma unroll
    for (int kt = 0; kt < 4; ++kt) {
        nk[kt] = (2 * gh + (kt >> 1)) * W_ + 2 * gw + (kt & 1);
        float s = 0.f;
        #pragma unroll
        for (int d = 0; d < HD_; ++d) s += q[d] * qkv[nk[kt] * 192 + 64 + hh * HD_ + d];
        e[kt] = __expf(s * SCALE_);
        esum += e[kt];
    }
    float inv = 1.f / esum;
    float o[HD_] = {};
    #pragma unroll
    for (int kt = 0; kt < 4; ++kt) {
        float pkt = e[kt] * inv;
        #pragma unroll
        for (int d = 0; d < HD_; ++d) o[d] += pkt * qkv[nk[kt] * 192 + 128 + hh * HD_ + d];
    }
    #pragma unroll
    for (int d = 0; d < HD_; ++d) ho[nq * 64 + hh * HD_ + d] = o[d];
}

// ---------------- launch ----------------
// Workspace (floats), no aliasing needed now (19.5 MB total):
//   low   [0        .. 294912)
//   high  [294912   .. 1474560)
//   hqkv  [1474560  .. 3244032)
//   ho    [3244032  .. 3833856)
//   lout  [3833856  .. 4423680)
//   Qb    [4423680  .. 4718592)   bf16 [4][9216][16]
//   Kb    [4718592  .. 4792320)   bf16 [4][2304][16]
//   Vt    [4792320  .. 4866048)   bf16 [4][16][2304]
extern "C" void kernel_launch(void* const* d_in, const int* in_sizes, int n_in,
                              void* d_out, int out_size, void* d_ws, size_t ws_size,
                              hipStream_t stream) {
    const float* x        = (const float*)d_in[0];
    const float* restore_w = (const float*)d_in[1];
    const float* restore_b = (const float*)d_in[2];
    const float* l_q_w    = (const float*)d_in[3];
    const float* l_kv_w   = (const float*)d_in[4];
    const float* l_proj_w = (const float*)d_in[5];
    const float* l_proj_b = (const float*)d_in[6];
    const float* h_qkv_w  = (const float*)d_in[7];
    const float* h_proj_w = (const float*)d_in[8];
    const float* h_proj_b = (const float*)d_in[9];
    float* out = (float*)d_out;

    float* ws    = (float*)d_ws;
    float* low   = ws;
    float* high  = ws + 294912;
    float* hqkv  = ws + 1474560;
    float* ho    = ws + 3244032;
    float* lout  = ws + 3833856;
    ushort_t* Qb = (ushort_t*)(ws + 4423680);
    ushort_t* Kb = (ushort_t*)(ws + 4718592);
    ushort_t* Vt = (ushort_t*)(ws + 4792320);

    // ---- shared prep ----
    k_avgpool<<<(NS_ * CDIM + 255) / 256, 256, 0, stream>>>(x, low);
    k_high<<<NTOK * CDIM / 1024, 256, 0, stream>>>(x, low, restore_w, restore_b, high);
    // Kb/Vt = low @ l_kv_w.T  (bf16, MFMA layouts)
    k_gemm_kv<<<dim3(NS_ / 64, 2), 256, 0, stream>>>(low, l_kv_w, Kb, Vt);

    // ---- high path ----
    k_gemm<<<dim3(NTOK / 64, 3), 256, 0, stream>>>(high, CDIM, h_qkv_w, nullptr, hqkv, 192, CDIM);
    k_hattn<<<(NPAIR + 255) / 256, 256, 0, stream>>>(hqkv, ho);
    k_gemm<<<dim3(NTOK / 64, 1), 256, 0, stream>>>(ho, LD_, h_proj_w, h_proj_b, out + 64, CDIM, LD_);

    // ---- low path ----
    k_gemm_q<<<NTOK / 64, 256, 0, stream>>>(x, l_q_w, Qb);
    k_lattn_mfma<<<LHEADS * (NTOK / 64), 256, 0, stream>>>(Qb, Kb, Vt, lout);
    k_gemm<<<dim3(NTOK / 64, 1), 256, 0, stream>>>(lout, LD_, l_proj_w, l_proj_b, out, CDIM, LD_);
}

// Round 12
// 178.949 us; speedup vs baseline: 1.3808x; 1.0174x over previous
//
#include <hip/hip_runtime.h>

// ---------------- problem constants ----------------
#define H_ 96
#define W_ 96
#define NTOK 9216            // H*W
#define CDIM 128
#define HS_ 48               // pooled H
#define NS_ 2304             // pooled tokens
#define KSP 1152             // keys per split (2-way split)
#define LHEADS 4
#define HD_ 16
#define LD_ 64
#define SCALE_ 0.25f
#define NPAIR 36864          // LHEADS*NTOK

typedef __attribute__((ext_vector_type(8))) short short8b;  // 8 x bf16
typedef __attribute__((ext_vector_type(4))) float f32x4;
typedef unsigned short ushort_t;

__device__ inline ushort_t f2bf(float x) {   // RNE float->bf16
    union { float f; unsigned u; } v; v.f = x;
    unsigned r = v.u + 0x7FFF + ((v.u >> 16) & 1);
    return (ushort_t)(r >> 16);
}

// ---------------- avg pool 2x2 ----------------
__global__ __launch_bounds__(256)
void k_avgpool(const float* __restrict__ x, float* __restrict__ low) {
    int idx = blockIdx.x * 256 + threadIdx.x;     // over NS_*CDIM
    if (idx >= NS_ * CDIM) return;
    int c = idx & 127;
    int p = idx >> 7;
    int ws_ = p % HS_, hs = p / HS_;
    int base = ((2 * hs) * W_ + 2 * ws_) * CDIM + c;
    float s = x[base] + x[base + CDIM] + x[base + W_ * CDIM] + x[base + W_ * CDIM + CDIM];
    low[idx] = 0.25f * s;
}

// ---------------- high = restore(pixelshuffle(low)) + b - x ----------------
__global__ __launch_bounds__(256)
void k_high(const float* __restrict__ x, const float* __restrict__ low,
            const float* __restrict__ rw, const float* __restrict__ rb,
            float* __restrict__ high) {
    __shared__ float w_s[32 * 128];   // w_s[ii*128+o] = rw[o*32+ii]
    int tid = threadIdx.x;
    #pragma unroll
    for (int k = 0; k < 16; ++k) {
        int idx = tid + k * 256;
        w_s[(idx & 31) * 128 + (idx >> 5)] = rw[idx];
    }
    __syncthreads();
    int base_i = blockIdx.x * 1024;           // 1024 elements per block
    #pragma unroll
    for (int k = 0; k < 4; ++k) {
        int idx = base_i + k * 256 + tid;     // over NTOK*CDIM
        int o = idx & 127;
        int n = idx >> 7;
        int h = n / W_, w = n % W_;
        int off = (h & 1) * 2 + (w & 1);
        const float* lrow = low + ((h >> 1) * HS_ + (w >> 1)) * CDIM + off;
        float acc = 0.f;
        #pragma unroll
        for (int ii = 0; ii < 32; ++ii) acc += lrow[ii * 4] * w_s[ii * 128 + o];
        high[idx] = acc + rb[o] - x[idx];
    }
}

// ---------------- generic tiled GEMM (fp32 out) ----------------
// BM=BN=64, BK=16, 256 threads, 4x4 per thread.
__global__ __launch_bounds__(256)
void k_gemm(const float* __restrict__ A, int lda,
            const float* __restrict__ Wt,          // (N,K) row-major
            const float* __restrict__ bias,        // may be null
            float* __restrict__ C, int ldc,
            int K) {
    __shared__ float As[16][68];
    __shared__ float Bs[16][68];
    int tid = threadIdx.x;
    int tx = tid & 15, ty = tid >> 4;
    int m0 = blockIdx.x * 64, n0 = blockIdx.y * 64;
    int lr = tid >> 2;
    int lk = (tid & 3) * 4;
    float acc[4][4] = {};
    for (int kk = 0; kk < K; kk += 16) {
        float4 av = *(const float4*)&A[(m0 + lr) * lda + kk + lk];
        float4 bv = *(const float4*)&Wt[(n0 + lr) * K + kk + lk];
        As[lk + 0][lr] = av.x; As[lk + 1][lr] = av.y;
        As[lk + 2][lr] = av.z; As[lk + 3][lr] = av.w;
        Bs[lk + 0][lr] = bv.x; Bs[lk + 1][lr] = bv.y;
        Bs[lk + 2][lr] = bv.z; Bs[lk + 3][lr] = bv.w;
        __syncthreads();
        #pragma unroll
        for (int k = 0; k < 16; ++k) {
            float a[4], bb[4];
            *(float4*)a  = *(const float4*)&As[k][ty * 4];
            *(float4*)bb = *(const float4*)&Bs[k][tx * 4];
            #pragma unroll
            for (int i = 0; i < 4; ++i)
                #pragma unroll
                for (int j = 0; j < 4; ++j) acc[i][j] += a[i] * bb[j];
        }
        __syncthreads();
    }
    #pragma unroll
    for (int i = 0; i < 4; ++i) {
        int m = m0 + ty * 4 + i;
        #pragma unroll
        for (int j = 0; j < 4; ++j) {
            int n = n0 + tx * 4 + j;
            float v = acc[i][j];
            if (bias) v += bias[n];
            C[m * ldc + n] = v;
        }
    }
}

// ---------------- lq GEMM -> Qb bf16 [4][NTOK][16], SCALE folded ----------------
__global__ __launch_bounds__(256)
void k_gemm_q(const float* __restrict__ A,           // x (NTOK x 128)
              const float* __restrict__ Wt,          // l_q_w (64 x 128)
              ushort_t* __restrict__ Qb) {
    __shared__ float As[16][68];
    __shared__ float Bs[16][68];
    int tid = threadIdx.x;
    int tx = tid & 15, ty = tid >> 4;
    int m0 = blockIdx.x * 64;
    int lr = tid >> 2;
    int lk = (tid & 3) * 4;
    float acc[4][4] = {};
    for (int kk = 0; kk < CDIM; kk += 16) {
        float4 av = *(const float4*)&A[(m0 + lr) * CDIM + kk + lk];
        float4 bv = *(const float4*)&Wt[lr * CDIM + kk + lk];
        As[lk + 0][lr] = av.x; As[lk + 1][lr] = av.y;
        As[lk + 2][lr] = av.z; As[lk + 3][lr] = av.w;
        Bs[lk + 0][lr] = bv.x; Bs[lk + 1][lr] = bv.y;
        Bs[lk + 2][lr] = bv.z; Bs[lk + 3][lr] = bv.w;
        __syncthreads();
        #pragma unroll
        for (int k = 0; k < 16; ++k) {
            float a[4], bb[4];
            *(float4*)a  = *(const float4*)&As[k][ty * 4];
            *(float4*)bb = *(const float4*)&Bs[k][tx * 4];
            #pragma unroll
            for (int i = 0; i < 4; ++i)
                #pragma unroll
                for (int j = 0; j < 4; ++j) acc[i][j] += a[i] * bb[j];
        }
        __syncthreads();
    }
    #pragma unroll
    for (int i = 0; i < 4; ++i) {
        int m = m0 + ty * 4 + i;
        #pragma unroll
        for (int j = 0; j < 4; ++j) {
            int n = tx * 4 + j;              // 0..63
            int h = n >> 4, d = n & 15;
            Qb[((size_t)h * NTOK + m) * 16 + d] = f2bf(acc[i][j] * SCALE_);
        }
    }
}

// ---------------- lkv GEMM -> Kb bf16 [4][NS][16], Vt bf16 [4][16][NS] ----------------
// Vt key order is PAIR-PERMUTED within each 32-key block: physical position
// p = 2*(k&15) + (k>>4), matching the pair-packed P layout in k_lattn_mfma
// (one u32 holds keys (c, c+16)). MFMA sums over k, so any consistent
// permutation of the contraction axis is exact.
__global__ __launch_bounds__(256)
void k_gemm_kv(const float* __restrict__ A,           // low (NS x 128)
               const float* __restrict__ Wt,          // l_kv_w (128 x 128)
               ushort_t* __restrict__ Kb, ushort_t* __restrict__ Vt) {
    __shared__ float As[16][68];
    __shared__ float Bs[16][68];
    int tid = threadIdx.x;
    int tx = tid & 15, ty = tid >> 4;
    int m0 = blockIdx.x * 64, n0 = blockIdx.y * 64;
    int lr = tid >> 2;
    int lk = (tid & 3) * 4;
    float acc[4][4] = {};
    for (int kk = 0; kk < CDIM; kk += 16) {
        float4 av = *(const float4*)&A[(m0 + lr) * CDIM + kk + lk];
        float4 bv = *(const float4*)&Wt[(n0 + lr) * CDIM + kk + lk];
        As[lk + 0][lr] = av.x; As[lk + 1][lr] = av.y;
        As[lk + 2][lr] = av.z; As[lk + 3][lr] = av.w;
        Bs[lk + 0][lr] = bv.x; Bs[lk + 1][lr] = bv.y;
        Bs[lk + 2][lr] = bv.z; Bs[lk + 3][lr] = bv.w;
        __syncthreads();
        #pragma unroll
        for (int k = 0; k < 16; ++k) {
            float a[4], bb[4];
            *(float4*)a  = *(const float4*)&As[k][ty * 4];
            *(float4*)bb = *(const float4*)&Bs[k][tx * 4];
            #pragma unroll
            for (int i = 0; i < 4; ++i)
                #pragma unroll
                for (int j = 0; j < 4; ++j) acc[i][j] += a[i] * bb[j];
        }
        __syncthreads();
    }
    #pragma unroll
    for (int i = 0; i < 4; ++i) {
        int m = m0 + ty * 4 + i;
        #pragma unroll
        for (int j = 0; j < 4; ++j) {
            int n = n0 + tx * 4 + j;          // 0..127
            ushort_t v = f2bf(acc[i][j]);
            if (n < 64) {                     // K part
                int h = n >> 4, d = n & 15;
                Kb[((size_t)h * NS_ + m) * 16 + d] = v;
            } else {                          // V part, transposed + pair-permuted
                int h = (n - 64) >> 4, d = (n - 64) & 15;
                int blk = m >> 5, km = m & 31;
                int pos = ((km & 15) << 1) | (km >> 4);
                Vt[((size_t)h * 16 + d) * NS_ + blk * 32 + pos] = v;
            }
        }
    }
}

// ---------------- low-freq attention: bf16 MFMA flash, 2-way key split ----------------
// grid (LHEADS*NTOK/64, 2). 256T = 4 independent waves; wave = 16 queries x
// 1152 keys of one split, one head. Per 32-key tile: 2x QK^T MFMA (d=16
// zero-padded), exp fp32, P pair-packed (u32 = keys (c,c+16)) into LDS rows
// padded to 20 u32 (80 B: writes 2-way-free, b128 reads minimal+aligned;
// round-11 lesson: [16][32]-u16 stores were an 8-way conflict, 3.3M cycles),
// 1 PV MFMA vs pair-permuted Vt. Partials (o, lsum) out via pacc/psum;
// max-free softmax makes the split-combine an exact sum.
__global__ __launch_bounds__(256)
void k_lattn_mfma(const ushort_t* __restrict__ Qb, const ushort_t* __restrict__ Kb,
                  const ushort_t* __restrict__ Vt, float* __restrict__ pacc,
                  float* __restrict__ psum) {
    __shared__ __align__(16) unsigned P_lds[4][16][20];
    int tid = threadIdx.x;
    int wid = tid >> 6;
    int lane = tid & 63;
    int g = lane >> 4, c = lane & 15;
    int head = blockIdx.x / (NTOK / 64);
    int qb = blockIdx.x % (NTOK / 64);
    int split = blockIdx.y;
    int q0 = qb * 64 + wid * 16;

    short8b zf = {0, 0, 0, 0, 0, 0, 0, 0};
    f32x4 zc = {0.f, 0.f, 0.f, 0.f};

    // Q A-frag (persistent): row=c, k=8g+e; zero for k>=16
    short8b qfrag = zf;
    if (g < 2)
        qfrag = *(const short8b*)(Qb + ((size_t)head * NTOK + q0 + c) * 16 + g * 8);

    const int kb0 = split * KSP;
    const ushort_t* kbase = Kb + (size_t)head * NS_ * 16 + (size_t)kb0 * 16;
    const ushort_t* vbase = Vt + ((size_t)head * 16 + c) * NS_ + kb0;

    f32x4 o = zc;
    float lsum[4] = {0.f, 0.f, 0.f, 0.f};

#define LOADT(KA, KB, VV, kt) do {                                            \
    if (g < 2) {                                                              \
        KA = *(const short8b*)(kbase + ((kt) + c) * 16 + g * 8);              \
        KB = *(const short8b*)(kbase + ((kt) + 16 + c) * 16 + g * 8);         \
    } else { KA = zf; KB = zf; }                                              \
    VV = *(const short8b*)(vbase + (kt) + 8 * g);                             \
} while (0)

#define COMPT(KA, KB, VV) do {                                                \
    f32x4 s0 = __builtin_amdgcn_mfma_f32_16x16x32_bf16(qfrag, KA, zc, 0, 0, 0); \
    f32x4 s1 = __builtin_amdgcn_mfma_f32_16x16x32_bf16(qfrag, KB, zc, 0, 0, 0); \
    _Pragma("unroll")                                                         \
    for (int r = 0; r < 4; ++r) {                                             \
        float p0 = __expf(s0[r]);                                             \
        float p1 = __expf(s1[r]);                                             \
        lsum[r] += p0 + p1;                                                   \
        P_lds[wid][4 * g + r][c] = ((unsigned)f2bf(p1) << 16) | f2bf(p0);     \
    }                                                                         \
    short8b pa = *(const short8b*)&P_lds[wid][c][4 * g];                      \
    o = __builtin_amdgcn_mfma_f32_16x16x32_bf16(pa, VV, o, 0, 0, 0);          \
} while (0)

    short8b kA, kB, vA, kA2, kB2, vA2;
    LOADT(kA, kB, vA, 0);
    int kt = 0;
    for (kt = 0; kt + 64 < KSP; kt += 64) {
        LOADT(kA2, kB2, vA2, kt + 32);
        COMPT(kA, kB, vA);
        LOADT(kA, kB, vA, kt + 64);
        COMPT(kA2, kB2, vA2);
    }
    LOADT(kA2, kB2, vA2, kt + 32);
    COMPT(kA, kB, vA);
    COMPT(kA2, kB2, vA2);
#undef LOADT
#undef COMPT

    // row-sum over the 16 key-cols within each 16-lane group, write partials
    #pragma unroll
    for (int r = 0; r < 4; ++r) {
        float s = lsum[r];
        s += __shfl_xor(s, 1);
        s += __shfl_xor(s, 2);
        s += __shfl_xor(s, 4);
        s += __shfl_xor(s, 8);
        size_t p = ((size_t)split * LHEADS + head) * NTOK + q0 + 4 * g + r;
        pacc[p * 16 + c] = o[r];
        if (c == 0) psum[p] = s;
    }
}

__global__ __launch_bounds__(256)
void k_lattn_combine(const float* __restrict__ pacc, const float* __restrict__ psum,
                     float* __restrict__ lout) {
    int idx = blockIdx.x * 256 + threadIdx.x;   // over LHEADS*NTOK*16
    if (idx >= LHEADS * NTOK * HD_) return;
    int d = idx & 15;
    int q = (idx >> 4) % NTOK;
    int h = (idx >> 4) / NTOK;
    size_t p0 = ((size_t)0 * LHEADS + h) * NTOK + q;
    size_t p1 = ((size_t)1 * LHEADS + h) * NTOK + q;
    float a = pacc[p0 * 16 + d] + pacc[p1 * 16 + d];
    float s = psum[p0] + psum[p1];
    lout[(size_t)q * LD_ + h * HD_ + d] = a / s;
}

// ---------------- high-freq 2x2 windowed attention ----------------
__global__ __launch_bounds__(256)
void k_hattn(const float* __restrict__ qkv, float* __restrict__ ho) {
    int idx = blockIdx.x * 256 + threadIdx.x;
    if (idx >= NPAIR) return;
    int t = idx & 3;
    int hh = (idx >> 2) & 3;
    int g = idx >> 4;
    int gh = g / 48, gw = g % 48;
    int nq = (2 * gh + (t >> 1)) * W_ + 2 * gw + (t & 1);
    float q[HD_];
    #pragma unroll
    for (int d = 0; d < HD_; ++d) q[d] = qkv[nq * 192 + hh * HD_ + d];
    float e[4], esum = 0.f;
    int nk[4];
    #pragma unroll
    for (int kt = 0; kt < 4; ++kt) {
        nk[kt] = (2 * gh + (kt >> 1)) * W_ + 2 * gw + (kt & 1);
        float s = 0.f;
        #pragma unroll
        for (int d = 0; d < HD_; ++d) s += q[d] * qkv[nk[kt] * 192 + 64 + hh * HD_ + d];
        e[kt] = __expf(s * SCALE_);
        esum += e[kt];
    }
    float inv = 1.f / esum;
    float o[HD_] = {};
    #pragma unroll
    for (int kt = 0; kt < 4; ++kt) {
        float pkt = e[kt] * inv;
        #pragma unroll
        for (int d = 0; d < HD_; ++d) o[d] += pkt * qkv[nk[kt] * 192 + 128 + hh * HD_ + d];
    }
    #pragma unroll
    for (int d = 0; d < HD_; ++d) ho[nq * 64 + hh * HD_ + d] = o[d];
}

// ---------------- launch ----------------
// Workspace (floats), 24.5 MB total (validated < 25.95 MB):
//   low   [0        .. 294912)
//   high  [294912   .. 1474560)
//   hqkv  [1474560  .. 3244032)
//   ho    [3244032  .. 3833856)
//   lout  [3833856  .. 4423680)
//   Qb    [4423680  .. 4718592)   bf16 [4][9216][16]
//   Kb    [4718592  .. 4792320)   bf16 [4][2304][16]
//   Vt    [4792320  .. 4866048)   bf16 [4][16][2304] (pair-permuted)
//   pacc  [4866048  .. 6045696)   f32 [2][4][9216][16]
//   psum  [6045696  .. 6119424)   f32 [2][4][9216]
extern "C" void kernel_launch(void* const* d_in, const int* in_sizes, int n_in,
                              void* d_out, int out_size, void* d_ws, size_t ws_size,
                              hipStream_t stream) {
    const float* x        = (const float*)d_in[0];
    const float* restore_w = (const float*)d_in[1];
    const float* restore_b = (const float*)d_in[2];
    const float* l_q_w    = (const float*)d_in[3];
    const float* l_kv_w   = (const float*)d_in[4];
    const float* l_proj_w = (const float*)d_in[5];
    const float* l_proj_b = (const float*)d_in[6];
    const float* h_qkv_w  = (const float*)d_in[7];
    const float* h_proj_w = (const float*)d_in[8];
    const float* h_proj_b = (const float*)d_in[9];
    float* out = (float*)d_out;

    float* ws    = (float*)d_ws;
    float* low   = ws;
    float* high  = ws + 294912;
    float* hqkv  = ws + 1474560;
    float* ho    = ws + 3244032;
    float* lout  = ws + 3833856;
    ushort_t* Qb = (ushort_t*)(ws + 4423680);
    ushort_t* Kb = (ushort_t*)(ws + 4718592);
    ushort_t* Vt = (ushort_t*)(ws + 4792320);
    float* pacc  = ws + 4866048;
    float* psum  = ws + 6045696;

    // ---- shared prep ----
    k_avgpool<<<(NS_ * CDIM + 255) / 256, 256, 0, stream>>>(x, low);
    k_high<<<NTOK * CDIM / 1024, 256, 0, stream>>>(x, low, restore_w, restore_b, high);
    // Kb/Vt = low @ l_kv_w.T  (bf16, MFMA layouts)
    k_gemm_kv<<<dim3(NS_ / 64, 2), 256, 0, stream>>>(low, l_kv_w, Kb, Vt);

    // ---- high path ----
    k_gemm<<<dim3(NTOK / 64, 3), 256, 0, stream>>>(high, CDIM, h_qkv_w, nullptr, hqkv, 192, CDIM);
    k_hattn<<<(NPAIR + 255) / 256, 256, 0, stream>>>(hqkv, ho);
    k_gemm<<<dim3(NTOK / 64, 1), 256, 0, stream>>>(ho, LD_, h_proj_w, h_proj_b, out + 64, CDIM, LD_);

    // ---- low path ----
    k_gemm_q<<<NTOK / 64, 256, 0, stream>>>(x, l_q_w, Qb);
    k_lattn_mfma<<<dim3(LHEADS * (NTOK / 64), 2), 256, 0, stream>>>(Qb, Kb, Vt, pacc, psum);
    k_lattn_combine<<<(LHEADS * NTOK * HD_ + 255) / 256, 256, 0, stream>>>(pacc, psum, lout);
    k_gemm<<<dim3(NTOK / 64, 1), 256, 0, stream>>>(lout, LD_, l_proj_w, l_proj_b, out, CDIM, LD_);
}